// Round 3
// baseline (91.618 us; speedup 1.0000x reference)
//
#include <hip/hip_runtime.h>
#include <cmath>

#define SITE 8
#define DIM 16
#define BATCH 8192

// Fully fused: one kernel, no workspace.
// 128 blocks x 256 threads; block handles 64 consecutive samples.
// Phase 1: build the 28 pattern-independent matrices (7 sites x 2 bits x
//          2 output-parities) + 2 head vectors into LDS.
// Phase 2: 8 concurrent samples (32 lanes each, within-wave => barrier-free
//          recurrence), 8 sequential rounds, direct float4 output.
__global__ __launch_bounds__(256) void fused_kernel(
    const int* __restrict__ data,         // (8192,8)
    const float* __restrict__ embedding,  // (8,2,16)
    const float* __restrict__ head_w,     // (32,32)
    const float* __restrict__ body_w,     // (7,32,32,32)
    float* __restrict__ out)              // (8192,2,32) = (8192,64)
{
    __shared__ float M[7][2][2][256];     // [site-1][bit][h][k*16+j]
    __shared__ float hv[2][16];           // head: [0]=e(bit0=0), [1]=o(bit0=1)
    __shared__ __align__(16) float st[8][2][16];  // per-concurrent-sample state

    const int tid = threadIdx.x;

    // ---- Phase 1: 28 matrices; thread t owns (k,j)=(t>>4, t&15) of each ----
    {
        const int k = tid >> 4;
        const int j = tid & 15;
        for (int r = 0; r < 28; ++r) {
            int s   = r >> 2;
            int bit = (r >> 1) & 1;
            int h   = r & 1;
            const float* g3  = body_w + s * 32768;
            const float* emb = embedding + (s + 1) * 32 + bit * 16;
            float acc = 0.f;
            if (bit == 0) {
                if (h == 0) {      // +sum_i emb0[i]*g3[k][i][j]          (LLL)
                    #pragma unroll
                    for (int i = 0; i < 16; ++i) acc += emb[i] * g3[k*1024 + i*32 + j];
                } else {           // +sum_i emb0[i]*g3[k+16][i][j+16]    (HLH)
                    #pragma unroll
                    for (int i = 0; i < 16; ++i) acc += emb[i] * g3[(k+16)*1024 + i*32 + (j+16)];
                }
            } else {
                if (h == 0) {      // -sum_i emb1[i]*g3[k+16][i+16][j]    (HHL)
                    #pragma unroll
                    for (int i = 0; i < 16; ++i) acc -= emb[i] * g3[(k+16)*1024 + (i+16)*32 + j];
                } else {           // +sum_i emb1[i]*g3[k][i+16][j+16]    (LHH)
                    #pragma unroll
                    for (int i = 0; i < 16; ++i) acc += emb[i] * g3[k*1024 + (i+16)*32 + (j+16)];
                }
            }
            M[s][bit][h][tid] = acc;
        }
    }

    // ---- Head vectors ----
    if (tid < 32) {
        int h = tid >> 4;
        int j = tid & 15;
        const float* emb = embedding + h * 16;   // site 0, row h
        float a = 0.f;
        if (h == 0) {
            #pragma unroll
            for (int k = 0; k < 16; ++k) a += emb[k] * head_w[k*32 + j];
        } else {
            #pragma unroll
            for (int k = 0; k < 16; ++k) a += emb[k] * head_w[(k+16)*32 + (j+16)];
        }
        hv[h][j] = tanhf(a);
    }
    __syncthreads();   // the ONLY block-wide barrier

    // ---- Phase 2: 64 samples, 8 concurrent (32 lanes each, wave-local) ----
    const int pl = tid >> 5;          // concurrent-sample slot 0..7
    const int h  = (tid >> 4) & 1;
    const int j  = tid & 15;
    const int lane16 = tid & 15;

    for (int rnd = 0; rnd < 8; ++rnd) {
        const int b = blockIdx.x * 64 + rnd * 8 + pl;
        // pattern id (all 32 lanes of the group redundantly; L1-hit)
        const int4* d4 = (const int4*)(data + b * 8);
        int4 w0 = d4[0];
        int4 w1 = d4[1];
        int id = (w0.x & 1) | ((w0.y & 1) << 1) | ((w0.z & 1) << 2) | ((w0.w & 1) << 3)
               | ((w1.x & 1) << 4) | ((w1.y & 1) << 5) | ((w1.z & 1) << 6) | ((w1.w & 1) << 7);

        // init: bit0==h -> hv[h], else 0
        float v = ((id & 1) == h) ? hv[h][j] : 0.f;
        st[pl][h][j] = v;             // same-wave LDS, no barrier needed

        #pragma unroll
        for (int s = 1; s < SITE; ++s) {
            int bit = (id >> s) & 1;
            const float* src = st[pl][h ^ bit];
            const float* m   = &M[s-1][bit][h][0];
            float a = 0.f;
            #pragma unroll
            for (int k = 0; k < 16; ++k) a += src[k] * m[k*16 + j];
            v = tanhf(a);
            st[pl][h][j] = v;         // lockstep within wave: reads precede write
        }

        // write row b: 16 float4 = [e(4), zeros(8), o(4)]; lanes 0..15 of group
        if ((tid & 31) < 16) {
            int q = lane16;
            float4 v4 = make_float4(0.f, 0.f, 0.f, 0.f);
            if (q < 4)        v4 = *(const float4*)&st[pl][0][q * 4];
            else if (q >= 12) v4 = *(const float4*)&st[pl][1][(q - 12) * 4];
            ((float4*)out)[b * 16 + q] = v4;
        }
    }
}

extern "C" void kernel_launch(void* const* d_in, const int* in_sizes, int n_in,
                              void* d_out, int out_size, void* d_ws, size_t ws_size,
                              hipStream_t stream) {
    const int*   data      = (const int*)d_in[0];
    const float* embedding = (const float*)d_in[1];
    const float* head_w    = (const float*)d_in[2];
    const float* body_w    = (const float*)d_in[3];
    (void)d_ws; (void)ws_size;

    fused_kernel<<<128, 256, 0, stream>>>(data, embedding, head_w, body_w,
                                          (float*)d_out);
}

// Round 4
// 67.220 us; speedup vs baseline: 1.3630x; 1.3630x over previous
//
#include <hip/hip_runtime.h>
#include <cmath>

#define SITE 8
#define DIM 16
#define BATCH 8192

// d_ws layout (floats):
//   [0 .. 7168)      M table: 28 matrices of 256 = [r][k*16+j], r = s*4+bit*2+h
//   [7168 .. 7200)   head vectors hv[2][16]
//   [8192 .. 16384)  pattern table pat[256][32]
#define WS_M   0
#define WS_HV  7168
#define WS_PAT 8192

__device__ __forceinline__ float fast_tanh(float a) {
    // 1 - 2/(exp(2a)+1): exact limits at +-inf, ~1e-7 rel error, one v_exp_f32.
    float t = __expf(2.0f * a);
    return 1.0f - 2.0f / (t + 1.0f);
}

// K1: build the 28 pattern-independent 16x16 matrices (float4-vectorized)
// plus the 2 head vectors. Blocks 0..6: 256 float4-tasks each; block 7: head.
__global__ __launch_bounds__(256) void build_kernel(
    const float* __restrict__ embedding,  // (8,2,16)
    const float* __restrict__ head_w,     // (32,32)
    const float* __restrict__ body_w,     // (7,32,32,32)
    float* __restrict__ ws)
{
    const int tid = threadIdx.x;
    if (blockIdx.x < 7) {
        int t = blockIdx.x * 256 + tid;   // 0 .. 1791 ; one float4 of one matrix
        int r = t >> 6;                   // matrix 0..27
        int rem = t & 63;
        int k  = rem >> 2;
        int j4 = rem & 3;
        int s   = r >> 2;
        int bit = (r >> 1) & 1;
        int h   = r & 1;
        int rowoff = (bit ^ h) << 4;      // +16 row block when bit^h
        int ioff   = bit << 4;            // +16 middle block when bit
        int coloff = (h << 4) + j4 * 4;   // +16 col block when h
        float sgn  = (bit && !h) ? -1.0f : 1.0f;
        const float* g3  = body_w + s * 32768 + (k + rowoff) * 1024 + ioff * 32 + coloff;
        const float* emb = embedding + (s + 1) * 32 + bit * 16;
        float4 acc = make_float4(0.f, 0.f, 0.f, 0.f);
        #pragma unroll
        for (int i = 0; i < 16; ++i) {
            float e = emb[i];
            float4 g = *(const float4*)(g3 + i * 32);
            acc.x += e * g.x; acc.y += e * g.y; acc.z += e * g.z; acc.w += e * g.w;
        }
        acc.x *= sgn; acc.y *= sgn; acc.z *= sgn; acc.w *= sgn;
        *(float4*)(ws + WS_M + r * 256 + k * 16 + j4 * 4) = acc;
    } else {
        // head vectors: hv[0][j] = tanh(emb00 . head_LL[:,j]), hv[1][j] = tanh(emb01 . head_HH[:,j])
        if (tid < 32) {
            int h = tid >> 4;
            int j = tid & 15;
            const float* emb = embedding + h * 16;   // site 0, row h
            float a = 0.f;
            if (h == 0) {
                #pragma unroll
                for (int k = 0; k < 16; ++k) a += emb[k] * head_w[k * 32 + j];
            } else {
                #pragma unroll
                for (int k = 0; k < 16; ++k) a += emb[k] * head_w[(k + 16) * 32 + (j + 16)];
            }
            ws[WS_HV + h * 16 + j] = fast_tanh(a);
        }
    }
}

// K2: one 32-lane group per pattern; M table staged in LDS; 7-step recurrence.
// 32 blocks x 256 threads (8 patterns per block).
__global__ __launch_bounds__(256) void recur_kernel(
    const float* __restrict__ ws_in,
    float* __restrict__ ws_out)
{
    __shared__ float Ml[7168];
    __shared__ __align__(16) float st[8][2][16];

    const int tid = threadIdx.x;
    // stage M: 1792 float4 / 256 threads = 7 each (coalesced)
    #pragma unroll
    for (int it = 0; it < 7; ++it) {
        int i4 = tid + 256 * it;
        ((float4*)Ml)[i4] = ((const float4*)(ws_in + WS_M))[i4];
    }
    __syncthreads();

    const int pl = tid >> 5;              // group slot 0..7
    const int p  = blockIdx.x * 8 + pl;   // pattern id
    const int h  = (tid >> 4) & 1;
    const int j  = tid & 15;

    // init from head vectors (global, L2-hot)
    float v = ((p & 1) == h) ? ws_in[WS_HV + h * 16 + j] : 0.f;
    st[pl][h][j] = v;                     // wave-local LDS: no barrier needed

    #pragma unroll
    for (int s = 1; s < SITE; ++s) {
        int bit = (p >> s) & 1;
        const float* src = st[pl][h ^ bit];
        const float* m   = Ml + ((s - 1) * 4 + bit * 2 + h) * 256;
        float a = 0.f;
        #pragma unroll
        for (int k = 0; k < 16; ++k) a += src[k] * m[k * 16 + j];
        v = fast_tanh(a);
        st[pl][h][j] = v;                 // lockstep within wave
    }

    ws_out[WS_PAT + p * 32 + h * 16 + j] = v;
}

// K3: scatter, one thread per output float4. Row b = [e(4), zeros(8), o(4)].
__global__ __launch_bounds__(256) void scatter_kernel(
    const int* __restrict__ data,     // (8192,8)
    const float4* __restrict__ pat4,  // (256,8) float4
    float4* __restrict__ out4)        // (8192,16) float4
{
    int gid = blockIdx.x * 256 + threadIdx.x;   // 0 .. 131071
    int b = gid >> 4;
    int q = gid & 15;
    const int4* d4 = (const int4*)(data + b * 8);
    int4 w0 = d4[0];
    int4 w1 = d4[1];
    int id = (w0.x & 1) | ((w0.y & 1) << 1) | ((w0.z & 1) << 2) | ((w0.w & 1) << 3)
           | ((w1.x & 1) << 4) | ((w1.y & 1) << 5) | ((w1.z & 1) << 6) | ((w1.w & 1) << 7);
    float4 v = make_float4(0.f, 0.f, 0.f, 0.f);
    if (q < 4)        v = pat4[id * 8 + q];
    else if (q >= 12) v = pat4[id * 8 + (q - 8)];
    out4[b * 16 + q] = v;
}

extern "C" void kernel_launch(void* const* d_in, const int* in_sizes, int n_in,
                              void* d_out, int out_size, void* d_ws, size_t ws_size,
                              hipStream_t stream) {
    const int*   data      = (const int*)d_in[0];
    const float* embedding = (const float*)d_in[1];
    const float* head_w    = (const float*)d_in[2];
    const float* body_w    = (const float*)d_in[3];
    float* ws = (float*)d_ws;

    build_kernel<<<8, 256, 0, stream>>>(embedding, head_w, body_w, ws);
    recur_kernel<<<32, 256, 0, stream>>>(ws, ws);
    scatter_kernel<<<(BATCH * 16) / 256, 256, 0, stream>>>(
        data, (const float4*)(ws + WS_PAT), (float4*)d_out);
}

// Round 5
// 66.369 us; speedup vs baseline: 1.3804x; 1.0128x over previous
//
#include <hip/hip_runtime.h>
#include <cmath>

#define SITE 8
#define DIM 16
#define BATCH 8192

// d_ws layout (floats), padded M: matrix r at r*272, row k at k*17 (16 used + 1 pad)
//   [0 .. 7616)      M table: 28 matrices, entry r*272 + k*17 + j
//   [7616 .. 7648)   head vectors hv[2][16]
#define WS_MPAD 272
#define WS_KPAD 17
#define WS_MEND 7616
#define WS_HV   7616

__device__ __forceinline__ float fast_tanh(float a) {
    // 1 - 2/(exp(2a)+1): exact limits at +-inf, ~1e-7 rel error, one v_exp_f32.
    float t = __expf(2.0f * a);
    return 1.0f - 2.0f / (t + 1.0f);
}

// Kernel A: build the 28 pattern-independent 16x16 matrices (float4 gathers)
// plus the 2 head vectors, into padded ws layout.
// Blocks 0..6: 256 float4-tasks each; block 7: head vectors.
__global__ __launch_bounds__(256) void build_kernel(
    const float* __restrict__ embedding,  // (8,2,16)
    const float* __restrict__ head_w,     // (32,32)
    const float* __restrict__ body_w,     // (7,32,32,32)
    float* __restrict__ ws)
{
    const int tid = threadIdx.x;
    if (blockIdx.x < 7) {
        int t = blockIdx.x * 256 + tid;   // 0 .. 1791 ; one float4 of one matrix
        int r = t >> 6;                   // matrix 0..27: r = s*4 + bit*2 + h
        int rem = t & 63;
        int k  = rem >> 2;
        int j4 = rem & 3;
        int s   = r >> 2;
        int bit = (r >> 1) & 1;
        int h   = r & 1;
        int rowoff = (bit ^ h) << 4;      // +16 row block when bit^h
        int ioff   = bit << 4;            // +16 middle block when bit
        int coloff = (h << 4) + j4 * 4;   // +16 col block when h
        float sgn  = (bit && !h) ? -1.0f : 1.0f;
        const float* g3  = body_w + s * 32768 + (k + rowoff) * 1024 + ioff * 32 + coloff;
        const float* emb = embedding + (s + 1) * 32 + bit * 16;
        float4 acc = make_float4(0.f, 0.f, 0.f, 0.f);
        #pragma unroll
        for (int i = 0; i < 16; ++i) {
            float e = emb[i];
            float4 g = *(const float4*)(g3 + i * 32);
            acc.x += e * g.x; acc.y += e * g.y; acc.z += e * g.z; acc.w += e * g.w;
        }
        float* dst = ws + r * WS_MPAD + k * WS_KPAD + j4 * 4;  // stride-17 rows: scalar stores
        dst[0] = sgn * acc.x; dst[1] = sgn * acc.y;
        dst[2] = sgn * acc.z; dst[3] = sgn * acc.w;
    } else {
        if (tid < 32) {
            int h = tid >> 4;
            int j = tid & 15;
            const float* emb = embedding + h * 16;   // site 0, row h
            float a = 0.f;
            if (h == 0) {
                #pragma unroll
                for (int k = 0; k < 16; ++k) a += emb[k] * head_w[k * 32 + j];
            } else {
                #pragma unroll
                for (int k = 0; k < 16; ++k) a += emb[k] * head_w[(k + 16) * 32 + (j + 16)];
            }
            ws[WS_HV + h * 16 + j] = fast_tanh(a);
        }
    }
}

// Kernel B: fused recurrence + scatter. 1024 blocks x 256 threads; block
// handles 8 samples (one 32-lane wave-local group per sample, barrier-free
// recurrence). M table staged via flat coalesced float4 copy.
__global__ __launch_bounds__(256) void recur_scatter_kernel(
    const int* __restrict__ data,     // (8192,8)
    const float* __restrict__ ws,
    float4* __restrict__ out4)        // (8192,16) float4
{
    __shared__ __align__(16) float Ml[WS_MEND];
    __shared__ __align__(16) float st[8][2][16];

    const int tid = threadIdx.x;

    // stage padded M table: 1904 float4 (pads carry garbage, never read)
    #pragma unroll
    for (int it = 0; it < 8; ++it) {
        int i4 = tid + 256 * it;
        if (i4 < WS_MEND / 4)
            ((float4*)Ml)[i4] = ((const float4*)ws)[i4];
    }

    const int pl = tid >> 5;              // group slot 0..7
    const int h  = (tid >> 4) & 1;
    const int j  = tid & 15;
    const int b  = blockIdx.x * 8 + pl;   // sample index

    // head value for this (h,j) — L2-hot global read, overlaps the LDS copy
    float hvv = ws[WS_HV + h * 16 + j];

    // pattern id from the sample's 8 bits
    const int4* d4 = (const int4*)(data + b * 8);
    int4 w0 = d4[0];
    int4 w1 = d4[1];
    int id = (w0.x & 1) | ((w0.y & 1) << 1) | ((w0.z & 1) << 2) | ((w0.w & 1) << 3)
           | ((w1.x & 1) << 4) | ((w1.y & 1) << 5) | ((w1.z & 1) << 6) | ((w1.w & 1) << 7);

    __syncthreads();

    // init: bit0==h -> hv[h], else 0
    float v = ((id & 1) == h) ? hvv : 0.f;
    st[pl][h][j] = v;                     // wave-local LDS, no barrier needed

    #pragma unroll
    for (int s = 1; s < SITE; ++s) {
        int bit = (id >> s) & 1;
        const float* src = st[pl][h ^ bit];
        const float* m   = Ml + ((s - 1) * 4 + bit * 2 + h) * WS_MPAD;
        float a0 = 0.f, a1 = 0.f, a2 = 0.f, a3 = 0.f;
        #pragma unroll
        for (int k = 0; k < 16; k += 4) {
            a0 += src[k]     * m[k * WS_KPAD + j];
            a1 += src[k + 1] * m[(k + 1) * WS_KPAD + j];
            a2 += src[k + 2] * m[(k + 2) * WS_KPAD + j];
            a3 += src[k + 3] * m[(k + 3) * WS_KPAD + j];
        }
        v = fast_tanh((a0 + a1) + (a2 + a3));
        st[pl][h][j] = v;                 // lockstep within wave
    }

    // write row b: 16 float4 = [e(4), zeros(8), o(4)]; lanes 0..15 of group
    if ((tid & 31) < 16) {
        int q = j;                        // 0..15
        float4 v4 = make_float4(0.f, 0.f, 0.f, 0.f);
        if (q < 4)        v4 = *(const float4*)&st[pl][0][q * 4];
        else if (q >= 12) v4 = *(const float4*)&st[pl][1][(q - 12) * 4];
        out4[b * 16 + q] = v4;
    }
}

extern "C" void kernel_launch(void* const* d_in, const int* in_sizes, int n_in,
                              void* d_out, int out_size, void* d_ws, size_t ws_size,
                              hipStream_t stream) {
    const int*   data      = (const int*)d_in[0];
    const float* embedding = (const float*)d_in[1];
    const float* head_w    = (const float*)d_in[2];
    const float* body_w    = (const float*)d_in[3];
    float* ws = (float*)d_ws;

    build_kernel<<<8, 256, 0, stream>>>(embedding, head_w, body_w, ws);
    recur_scatter_kernel<<<BATCH / 8, 256, 0, stream>>>(data, ws, (float4*)d_out);
}